// Round 4
// baseline (9328.476 us; speedup 1.0000x reference)
//
#include <hip/hip_runtime.h>
#include <stdint.h>

// StackedRNN depth-3, B=16, T=2048, H=256. Inputs fp32, output fp32.
// Round 4: pre-activation split. 9 WGs: 3 serial (one per depth) + 6 helper
// (2 per depth). Helpers compute P[t] = b + W_ih @ inp_t (no recurrence!)
// chunk-by-chunk, gated on the upstream serial stage's progress flag, and
// store P fp32 into the OUTPUT slot out[b,t,k,:]. The serial WG reads P as
// accumulator init (2-step prefetch), runs only the K=256 W_hh @ h_{t-1}
// half (8 MFMAs/wave/step), then overwrites the slot with masked h.
// Bit-identical numerics to the 2133us baseline (same fp16 roundings, same
// fp32 MFMA accumulation order: bias -> inp terms -> h terms).
// Serial keeps round-3's verified structure: 512 threads (8 waves, 2/SIMD),
// XOR-swizzled LDS (h panel only, 2 x 8KB ping-pong), exp2 tanh, light
// barrier (no vmcnt drain) on 7/8 steps, full __syncthreads every 8th.

#define TT 2048
#define HH 256

typedef _Float16 h16x8 __attribute__((ext_vector_type(8)));
typedef float f32x4 __attribute__((ext_vector_type(4)));

__device__ __forceinline__ unsigned pkrtz(float a, float b) {
  return __builtin_bit_cast(unsigned, __builtin_amdgcn_cvt_pkrtz(a, b));
}

// pack 8 fp32 -> 8 fp16 (RTZ, matches the original loader's pkrtz path)
__device__ __forceinline__ h16x8 pack8(float4 a, float4 b) {
  uint4 u = make_uint4(pkrtz(a.x, a.y), pkrtz(a.z, a.w),
                       pkrtz(b.x, b.y), pkrtz(b.z, b.w));
  return __builtin_bit_cast(h16x8, u);
}

// tanh(x) = 1 - 2e/(1+e), e = e^{-2x} = exp2(-2*log2(e)*x).  ~1e-6 err.
__device__ __forceinline__ float tanh_fast(float x) {
  float xm = fmaxf(x, -15.0f);
  float e = __builtin_amdgcn_exp2f(xm * -2.88539008177793f);
  float r = __builtin_amdgcn_rcpf(1.0f + e);
  return __builtin_fmaf(-2.0f * e, r, 1.0f);
}

__device__ __forceinline__ void spin_ge(int* p, int need) {
  while (__hip_atomic_load(p, __ATOMIC_ACQUIRE, __HIP_MEMORY_SCOPE_AGENT) < need)
    __builtin_amdgcn_s_sleep(2);
}

// Light barrier: order LDS writes (lgkmcnt) + store-data reads (expcnt)
// but leave global loads/stores in flight (T4: no vmcnt drain in the loop).
__device__ __forceinline__ void light_barrier() {
  asm volatile("s_waitcnt expcnt(0) lgkmcnt(0)" ::: "memory");
  __builtin_amdgcn_s_barrier();
}

// Flags: serial stage k progress at flags[k*64] (value t => steps < t of h
// are stored+visible). Helper (k, j) progress at flags[(3 + k*2 + j)*64]
// (value s => P for steps < s of its block written+visible).
__global__ __launch_bounds__(512, 2)
void stacked_rnn(const float* __restrict__ x,
                 const int* __restrict__ seq_lens,
                 const float* __restrict__ Wih,
                 const float* __restrict__ Whh,
                 const float* __restrict__ bias,
                 float* __restrict__ out,
                 int* flags) {
  const int bid = (int)blockIdx.x;
  const int tid = (int)threadIdx.x;
  const int w = tid >> 6;              // wave 0..7 -> rows [32w, 32w+32)
  const int lane = tid & 63;
  const int q = lane >> 4;
  const int n = lane & 15;             // batch column

  __shared__ __align__(16) unsigned short Bsm[2][4096];  // 2 x 8KB h ping-pong

  if (bid >= 3) {
    // ================= helper: P[t] = b + W_ih @ inp_t =================
    const int kh = (bid - 3) >> 1;     // stage 0..2
    const int jh = (bid - 3) & 1;      // block: steps [jh*1024, jh*1024+1024)
    int* fMe = flags + (3 + kh * 2 + jh) * 64;
    int* fUp = flags + (kh - 1) * 64;  // upstream serial (kh>0 only)

    // W_ih A-fragments (fp16 RNE, identical to baseline's kt<8 frags)
    h16x8 wf[2][8];
    {
      const float* wih_s = Wih + kh * (HH * HH);
#pragma unroll
      for (int mti = 0; mti < 2; ++mti) {
        const int fA = w * 32 + mti * 16 + n;
#pragma unroll
        for (int kt = 0; kt < 8; ++kt) {
          const float* src = wih_s + fA * HH + kt * 32 + q * 8;
          float4 a0 = ((const float4*)src)[0];
          float4 a1 = ((const float4*)src)[1];
          h16x8 f;
          f[0] = (_Float16)a0.x; f[1] = (_Float16)a0.y;
          f[2] = (_Float16)a0.z; f[3] = (_Float16)a0.w;
          f[4] = (_Float16)a1.x; f[5] = (_Float16)a1.y;
          f[6] = (_Float16)a1.z; f[7] = (_Float16)a1.w;
          wf[mti][kt] = f;
        }
      }
    }
    f32x4 biasv[2];
#pragma unroll
    for (int mti = 0; mti < 2; ++mti)
#pragma unroll
      for (int r = 0; r < 4; ++r)
        biasv[mti][r] = bias[kh * HH + w * 32 + mti * 16 + q * 4 + r];

    // per-lane input base: 8 contiguous floats at k = kt*32 + q*8
    const float* ibase;
    int istr;
    if (kh == 0) { ibase = x + n * (TT * HH) + q * 8; istr = HH; }
    else { ibase = out + (n * (TT * 3) + (kh - 1)) * HH + q * 8; istr = 3 * HH; }

    float* pp = out + (n * (TT * 3) + kh) * HH + w * 32 + q * 4
                + (jh * 1024) * (3 * HH);

    for (int c = jh * 1024; c < jh * 1024 + 1024; c += 16) {
      if (kh > 0) {                    // need upstream h for steps c..c+15
        if (tid == 0) spin_ge(fUp, c + 16);
        __syncthreads();
      }
      for (int tt = 0; tt < 16; ++tt) {
        const float* bs = ibase + (c + tt) * istr;
        f32x4 acc0 = biasv[0], acc1 = biasv[1];
#pragma unroll
        for (int kt = 0; kt < 8; ++kt) {
          float4 b0 = ((const float4*)(bs + kt * 32))[0];
          float4 b1 = ((const float4*)(bs + kt * 32 + 4))[0];
          h16x8 bf = pack8(b0, b1);
          acc0 = __builtin_amdgcn_mfma_f32_16x16x32_f16(wf[0][kt], bf, acc0, 0, 0, 0);
          acc1 = __builtin_amdgcn_mfma_f32_16x16x32_f16(wf[1][kt], bf, acc1, 0, 0, 0);
        }
        *(f32x4*)(pp) = acc0;
        *(f32x4*)(pp + 16) = acc1;
        pp += 3 * HH;
      }
      __syncthreads();                 // drains all threads' P stores (vmcnt)
      if (tid == 0)
        __hip_atomic_store(fMe, c + 16, __ATOMIC_RELEASE,
                           __HIP_MEMORY_SCOPE_AGENT);
    }
    return;
  }

  // ================= serial: h_t = tanh(P[t] + W_hh @ h_{t-1}) ============
  const int ks = bid;
  int* flag_me = flags + ks * 64;
  int* fH0 = flags + (3 + ks * 2) * 64;
  int* fH1 = flags + (3 + ks * 2 + 1) * 64;

  // W_hh A-fragments (identical bits to baseline's kt 8..15 frags)
  h16x8 wf[2][8];
  {
    const float* whh_s = Whh + ks * (HH * HH);
#pragma unroll
    for (int mti = 0; mti < 2; ++mti) {
      const int fA = w * 32 + mti * 16 + n;
#pragma unroll
      for (int kt = 0; kt < 8; ++kt) {
        const float* src = whh_s + fA * HH + kt * 32 + q * 8;
        float4 a0 = ((const float4*)src)[0];
        float4 a1 = ((const float4*)src)[1];
        h16x8 f;
        f[0] = (_Float16)a0.x; f[1] = (_Float16)a0.y;
        f[2] = (_Float16)a0.z; f[3] = (_Float16)a0.w;
        f[4] = (_Float16)a1.x; f[5] = (_Float16)a1.y;
        f[6] = (_Float16)a1.z; f[7] = (_Float16)a1.w;
        wf[mti][kt] = f;
      }
    }
  }

  const int sl = seq_lens[n];

  // h panel (K=256): granule u = k>>3 (0..31), frag kt at rd{E,O} + kt*512
  const int rdE = (q * 16 + (n ^ q)) * 8;        // even kt: u&7 = q
  const int rdO = (q * 16 + (n ^ q ^ 4)) * 8;    // odd  kt: u&7 = q+4
  int hofs[2];
#pragma unroll
  for (int mti = 0; mti < 2; ++mti) {
    const int u = w * 4 + mti * 2 + (q >> 1);
    hofs[mti] = (u * 16 + (n ^ (u & 7))) * 8 + (q & 1) * 4;
  }

  // zero h buf0 (h_{-1} = 0): 8KB, one b128 store per thread
  ((uint4*)&Bsm[0][0])[tid] = make_uint4(0, 0, 0, 0);
  if (tid == 0) spin_ge(fH0, 18);      // P[0..17] ready (covers preload+chunk0)
  __syncthreads();

  float* outp = out + (n * (TT * 3) + ks) * HH + w * 32 + q * 4;
  // preload P[0], P[1] into carry regs
  float4 curP0 = *(const float4*)(outp);
  float4 curP1 = *(const float4*)(outp + 16);
  float4 nxtP0 = *(const float4*)(outp + 3 * HH);
  float4 nxtP1 = *(const float4*)(outp + 3 * HH + 16);

  for (int t = 0; t < TT; ++t) {
    unsigned short* Bp = Bsm[t & 1];
    unsigned short* Bq = Bsm[(t & 1) ^ 1];

    // ---- publish (multiples of 8; stores drained by the full barrier at
    //      the end of iter t-1, since (t-1)&7 == 7)
    if ((t & 7) == 0 && t > 0 && ks < 2 && tid == 0)
      __hip_atomic_store(flag_me, t, __ATOMIC_RELEASE,
                         __HIP_MEMORY_SCOPE_AGENT);
    // ---- P gate: iters t..t+15 prefetch P up to step t+17 -> need t+18
    if ((t & 15) == 0 && t > 0) {
      if (tid == 0) {
        int need = t + 18;
        if (need > TT) need = TT;
        if (need <= 1024) spin_ge(fH0, need);
        else              spin_ge(fH1, need);
      }
      __syncthreads();
    }

    // ---- issue P prefetch for step t+2
    const bool more2 = (t + 2 < TT);
    float4 pf0, pf1;
    if (more2) {
      pf0 = *(const float4*)(outp + 2 * (3 * HH));
      pf1 = *(const float4*)(outp + 2 * (3 * HH) + 16);
    }

    // ---- GEMM: acc = P[t] + W_hh @ h_{t-1}   (K=256, 8 MFMAs/tile)
    f32x4 acc[2] = {__builtin_bit_cast(f32x4, curP0),
                    __builtin_bit_cast(f32x4, curP1)};
#pragma unroll
    for (int kt = 0; kt < 8; ++kt) {
      const int ofs = ((kt & 1) ? rdO : rdE) + kt * 512;
      h16x8 bf = *(const h16x8*)&Bp[ofs];
      acc[0] = __builtin_amdgcn_mfma_f32_16x16x32_f16(wf[0][kt], bf, acc[0], 0, 0, 0);
      acc[1] = __builtin_amdgcn_mfma_f32_16x16x32_f16(wf[1][kt], bf, acc[1], 0, 0, 0);
    }

    // ---- tanh + masked fp32 output store (overwrites the P slot with h)
    const bool live = (t < sl);
    uint2 hpk[2];
#pragma unroll
    for (int mti = 0; mti < 2; ++mti) {
      float h0 = tanh_fast(acc[mti][0]);
      float h1 = tanh_fast(acc[mti][1]);
      float h2 = tanh_fast(acc[mti][2]);
      float h3 = tanh_fast(acc[mti][3]);
      hpk[mti].x = pkrtz(h0, h1);
      hpk[mti].y = pkrtz(h2, h3);
      float4 od;
      od.x = live ? h0 : 0.0f;
      od.y = live ? h1 : 0.0f;
      od.z = live ? h2 : 0.0f;
      od.w = live ? h3 : 0.0f;
      *(float4*)(outp + mti * 16) = od;
    }
    outp += 3 * HH;

    // ---- write h_t into buf p^1 (inp staging is gone)
    if (t + 1 < TT) {
      *(uint2*)&Bq[hofs[0]] = hpk[0];
      *(uint2*)&Bq[hofs[1]] = hpk[1];
    }
    // ---- rotate P carry regs
    curP0 = nxtP0; curP1 = nxtP1;
    if (more2) { nxtP0 = pf0; nxtP1 = pf1; }

    // ---- light barrier (no vmcnt drain) except every 8th step
    if ((t & 7) == 7) {
      __syncthreads();
    } else {
      light_barrier();
    }
  }

  if (ks < 2 && tid == 0)
    __hip_atomic_store(flag_me, TT, __ATOMIC_RELEASE, __HIP_MEMORY_SCOPE_AGENT);
}

extern "C" void kernel_launch(void* const* d_in, const int* in_sizes, int n_in,
                              void* d_out, int out_size, void* d_ws, size_t ws_size,
                              hipStream_t stream) {
  (void)in_sizes; (void)n_in; (void)out_size; (void)ws_size;
  const float* x   = (const float*)d_in[0];
  const int*   sl  = (const int*)d_in[1];
  const float* wih = (const float*)d_in[2];
  const float* whh = (const float*)d_in[3];
  const float* b   = (const float*)d_in[4];

  // zero the progress flags (ws is poisoned 0xAA before every launch)
  (void)hipMemsetAsync(d_ws, 0, 4096, stream);
  hipLaunchKernelGGL(stacked_rnn, dim3(9), dim3(512), 0, stream,
                     x, sl, wih, whh, b, (float*)d_out, (int*)d_ws);
}

// Round 5
// 2345.350 us; speedup vs baseline: 3.9774x; 3.9774x over previous
//
#include <hip/hip_runtime.h>
#include <stdint.h>

// StackedRNN depth-3, B=16, T=2048, H=256. Inputs fp32, output fp32.
// 3 persistent workgroups (one per depth), 512 threads (8 waves, 2/SIMD).
// Weights fp16-resident in VGPRs (wf[2][16] = 128 VGPR/lane), batch=16 in
// MFMA N, depth pipelined through d_out with agent-scope progress flags.
// Single barrier/step (ping-pong LDS B), XOR-swizzled LDS (conflict-free),
// exp2-based tanh, 2-step-deep global prefetch. Light per-step barrier
// (no vmcnt drain) on 7/8 steps, full __syncthreads every 8th (backs the
// flag publish).  [R4 lesson: cross-WG P-handoff at 16-step granularity
// costs us ~4x — per-step critical path must stay inside one WG.]
// This round (vs verified 2133us R3): accumulators split into even/odd-kt
// partials -> 4 independent 8-deep MFMA chains instead of 2x16-deep,
// merged with 8 v_add_f32 before tanh. Halves MFMA dependent-chain
// latency in the GEMM phase; everything else byte-identical to R3.

#define TT 2048
#define HH 256

typedef _Float16 h16x8 __attribute__((ext_vector_type(8)));
typedef float f32x4 __attribute__((ext_vector_type(4)));

__device__ __forceinline__ unsigned pkrtz(float a, float b) {
  return __builtin_bit_cast(unsigned, __builtin_amdgcn_cvt_pkrtz(a, b));
}

// tanh(x) = 1 - 2e/(1+e), e = e^{-2x} = exp2(-2*log2(e)*x).  ~1e-6 err.
// clamp low side so e stays finite (avoids inf*0 NaN).
__device__ __forceinline__ float tanh_fast(float x) {
  float xm = fmaxf(x, -15.0f);
  float e = __builtin_amdgcn_exp2f(xm * -2.88539008177793f);
  float r = __builtin_amdgcn_rcpf(1.0f + e);
  return __builtin_fmaf(-2.0f * e, r, 1.0f);
}

__device__ __forceinline__ void spin_ge(int* p, int need) {
  while (__hip_atomic_load(p, __ATOMIC_ACQUIRE, __HIP_MEMORY_SCOPE_AGENT) < need)
    __builtin_amdgcn_s_sleep(2);
}

// Light barrier: order LDS writes (lgkmcnt) + store-data reads (expcnt)
// but leave global loads/stores in flight across the barrier (T4: never
// drain vmcnt in the main loop). "memory" clobber pins memory-op order.
__device__ __forceinline__ void light_barrier() {
  asm volatile("s_waitcnt expcnt(0) lgkmcnt(0)" ::: "memory");
  __builtin_amdgcn_s_barrier();
}

// LDS B layout (fp16, K=512 = [inp 256 | h 256]):
//   granule (16B) for (k,n): u = (k>>5)*4 + ((k>>3)&3), v = n, j = k&7
//   half-index = (u*16 + (v ^ (u&7)))*8 + j     (XOR swizzle kills write
//   conflicts; reads at fixed u keep all 16 v' distinct -> conflict-free)
__global__ __launch_bounds__(512, 2)
void stacked_rnn(const float* __restrict__ x,
                 const int* __restrict__ seq_lens,
                 const float* __restrict__ Wih,
                 const float* __restrict__ Whh,
                 const float* __restrict__ bias,
                 float* __restrict__ out,
                 int* flags) {
  const int ks = blockIdx.x;           // depth stage 0..2
  const int tid = (int)threadIdx.x;
  const int w = tid >> 6;              // wave 0..7 -> rows [32w, 32w+32)
  const int lane = tid & 63;
  const int q = lane >> 4;
  const int n = lane & 15;             // batch column

  __shared__ __align__(16) unsigned short Bsm[2][8192];   // 2 x 16KB ping-pong

  int* flag_up = flags + (ks - 1) * 64;
  int* flag_me = flags + ks * 64;

  // ---- persistent weight A-fragments (fp16, RTN): kt<8 = W_ih, kt>=8 = W_hh
  h16x8 wf[2][16];
  {
    const float* wih_s = Wih + ks * (HH * HH);
    const float* whh_s = Whh + ks * (HH * HH);
#pragma unroll
    for (int mti = 0; mti < 2; ++mti) {
      const int fA = w * 32 + mti * 16 + n;      // A row = lane&15
#pragma unroll
      for (int kt = 0; kt < 16; ++kt) {
        const int col = (kt & 7) * 32 + q * 8;   // A k = quad*8 + j
        const float* src = (kt < 8) ? (wih_s + fA * HH + col)
                                    : (whh_s + fA * HH + col);
        float4 a0 = ((const float4*)src)[0];
        float4 a1 = ((const float4*)src)[1];
        h16x8 f;
        f[0] = (_Float16)a0.x; f[1] = (_Float16)a0.y;
        f[2] = (_Float16)a0.z; f[3] = (_Float16)a0.w;
        f[4] = (_Float16)a1.x; f[5] = (_Float16)a1.y;
        f[6] = (_Float16)a1.z; f[7] = (_Float16)a1.w;
        wf[mti][kt] = f;
      }
    }
  }

  // ---- bias in C-layout (row = q*4+r, col = n), exact fp32
  f32x4 biasv[2];
#pragma unroll
  for (int mti = 0; mti < 2; ++mti)
#pragma unroll
    for (int r = 0; r < 4; ++r)
      biasv[mti][r] = bias[ks * HH + w * 32 + mti * 16 + q * 4 + r];

  const int sl = seq_lens[n];

  // ---- fragment read offsets (halves): frag kt at rd{E,O} + kt*512
  const int rdE = (q * 16 + (n ^ q)) * 8;        // even kt: u&7 = q
  const int rdO = (q * 16 + (n ^ q ^ 4)) * 8;    // odd  kt: u&7 = q+4

  // ---- h-repack write offsets (uint2 = 4 halves, j0 = (q&1)*4)
  int hofs[2];
#pragma unroll
  for (int mti = 0; mti < 2; ++mti) {
    const int u = (8 + w) * 4 + mti * 2 + (q >> 1);
    hofs[mti] = (u * 16 + (n ^ (u & 7))) * 8 + (q & 1) * 4;
  }

  // ---- loader: 512 chunks of 8 floats = {n 0..15} x {k8 0..31}, 1/thread
  const int n_l = tid >> 5;
  const int k8  = tid & 31;
  const int u_l = (k8 >> 2) * 4 + (k8 & 3);
  const int ldst = (u_l * 16 + (n_l ^ (u_l & 7))) * 8;

  const float* src_base;
  int src_stride;
  if (ks == 0) {
    src_base = x + ((n_l * TT) << 8) + (k8 << 3);
    src_stride = HH;
  } else {
    src_base = out + (((n_l * TT) * 3 + (ks - 1)) << 8) + (k8 << 3);
    src_stride = 3 * HH;
  }

  // ---- zero h-half of buf0 (h_{-1} = 0): 8KB, one b128 store per thread
  ((uint4*)&Bsm[0][4096])[tid] = make_uint4(0, 0, 0, 0);
  if (ks > 0 && tid == 0) spin_ge(flag_up, 18);   // covers preload + chunk 0
  __syncthreads();

  // ---- preload inp_0 -> buf0, inp_1 -> pfB, pf pointer at t=2
  {
    float4 c0 = ((const float4*)src_base)[0];
    float4 c1 = ((const float4*)src_base)[1];
    *(uint4*)&Bsm[0][ldst] = make_uint4(pkrtz(c0.x, c0.y), pkrtz(c0.z, c0.w),
                                        pkrtz(c1.x, c1.y), pkrtz(c1.z, c1.w));
  }
  float4 pfB0 = ((const float4*)(src_base + src_stride))[0];
  float4 pfB1 = ((const float4*)(src_base + src_stride))[1];
  const float* src_pf = src_base + 2 * src_stride;
  __syncthreads();

  float* outp = out + ((n * TT) * 3 + ks) * HH + w * 32 + q * 4;

  for (int t = 0; t < TT; ++t) {
    unsigned short* Bp = Bsm[t & 1];
    unsigned short* Bq = Bsm[(t & 1) ^ 1];

    // ---- publish (multiples of 8; stores drained by the full barrier at
    //      the end of iter t-1, since (t-1)&7 == 7)
    if ((t & 7) == 0 && t > 0 && ks < 2 && tid == 0)
      __hip_atomic_store(flag_me, t, __ATOMIC_RELEASE,
                         __HIP_MEMORY_SCOPE_AGENT);
    // ---- chunk gate: iters t..t+15 load steps t+2..t+17 -> need flag t+18
    if ((t & 15) == 0 && t > 0 && ks > 0) {
      if (tid == 0) {
        int need = t + 18;
        if (need > TT) need = TT;
        spin_ge(flag_up, need);
      }
      __syncthreads();
    }

    // ---- issue global prefetch for inp_{t+2}
    float4 pfA0, pfA1;
    const bool more2 = (t + 2 < TT);
    if (more2) {
      pfA0 = ((const float4*)src_pf)[0];
      pfA1 = ((const float4*)src_pf)[1];
    }
    src_pf += src_stride;

    // ---- GEMM: acc = bias + Wcat @ [inp_t ; h_{t-1}]
    //      4 independent 8-deep chains (even/odd kt) to halve MFMA
    //      dependent-chain latency; merged before tanh.
    f32x4 accE[2] = {biasv[0], biasv[1]};
    f32x4 accO[2] = {{0.f, 0.f, 0.f, 0.f}, {0.f, 0.f, 0.f, 0.f}};
#pragma unroll
    for (int kt = 0; kt < 16; ++kt) {
      const int ofs = ((kt & 1) ? rdO : rdE) + kt * 512;
      h16x8 bf = *(const h16x8*)&Bp[ofs];
      if (kt & 1) {
        accO[0] = __builtin_amdgcn_mfma_f32_16x16x32_f16(wf[0][kt], bf, accO[0], 0, 0, 0);
        accO[1] = __builtin_amdgcn_mfma_f32_16x16x32_f16(wf[1][kt], bf, accO[1], 0, 0, 0);
      } else {
        accE[0] = __builtin_amdgcn_mfma_f32_16x16x32_f16(wf[0][kt], bf, accE[0], 0, 0, 0);
        accE[1] = __builtin_amdgcn_mfma_f32_16x16x32_f16(wf[1][kt], bf, accE[1], 0, 0, 0);
      }
    }
    f32x4 acc[2];
    acc[0] = accE[0] + accO[0];
    acc[1] = accE[1] + accO[1];

    // ---- tanh + masked fp32 output store (h kept unmasked for recurrence)
    const bool live = (t < sl);
    uint2 hpk[2];
#pragma unroll
    for (int mti = 0; mti < 2; ++mti) {
      float h0 = tanh_fast(acc[mti][0]);
      float h1 = tanh_fast(acc[mti][1]);
      float h2 = tanh_fast(acc[mti][2]);
      float h3 = tanh_fast(acc[mti][3]);
      hpk[mti].x = pkrtz(h0, h1);
      hpk[mti].y = pkrtz(h2, h3);
      float4 od;
      od.x = live ? h0 : 0.0f;
      od.y = live ? h1 : 0.0f;
      od.z = live ? h2 : 0.0f;
      od.w = live ? h3 : 0.0f;
      *(float4*)(outp + mti * 16) = od;
    }
    outp += 3 * HH;

    // ---- write buf p^1: inp_{t+1} (from pfB) + h_t (repack)
    if (t + 1 < TT) {
      *(uint4*)&Bq[ldst] = make_uint4(pkrtz(pfB0.x, pfB0.y), pkrtz(pfB0.z, pfB0.w),
                                      pkrtz(pfB1.x, pfB1.y), pkrtz(pfB1.z, pfB1.w));
      *(uint2*)&Bq[hofs[0]] = hpk[0];
      *(uint2*)&Bq[hofs[1]] = hpk[1];
      if (more2) { pfB0 = pfA0; pfB1 = pfA1; }
    }

    // ---- the one per-step barrier: light (no vmcnt drain) except every
    //      8th step, whose full drain backs the next publish. Uniform branch.
    if ((t & 7) == 7) {
      __syncthreads();
    } else {
      light_barrier();
    }
  }

  if (ks < 2 && tid == 0)
    __hip_atomic_store(flag_me, TT, __ATOMIC_RELEASE, __HIP_MEMORY_SCOPE_AGENT);
}

extern "C" void kernel_launch(void* const* d_in, const int* in_sizes, int n_in,
                              void* d_out, int out_size, void* d_ws, size_t ws_size,
                              hipStream_t stream) {
  (void)in_sizes; (void)n_in; (void)out_size; (void)ws_size;
  const float* x   = (const float*)d_in[0];
  const int*   sl  = (const int*)d_in[1];
  const float* wih = (const float*)d_in[2];
  const float* whh = (const float*)d_in[3];
  const float* b   = (const float*)d_in[4];

  // zero the progress flags (ws is poisoned 0xAA before every launch)
  (void)hipMemsetAsync(d_ws, 0, 1024, stream);
  hipLaunchKernelGGL(stacked_rnn, dim3(3), dim3(512), 0, stream,
                     x, sl, wih, whh, b, (float*)d_out, (int*)d_ws);
}